// Round 7
// baseline (442.197 us; speedup 1.0000x reference)
//
#include <hip/hip_runtime.h>
#include <hip/hip_bf16.h>

#define N_NODES 8192
#define IN_F    256
#define OUT_F   64
#define ALPHA   0.3f
#define MBIAS   20.0f            // >= max dst_j; softmax exact after l-division
#define CSPL    8                // column splits
#define COLS_PER (N_NODES / CSPL)    // 1024
#define NTILES  (COLS_PER / 64)      // 16
#define LDP     72               // padded LDS row stride (u16): 64 + 8, 16B-aligned

typedef unsigned short u16;
typedef unsigned int   u32;
typedef __attribute__((ext_vector_type(8))) short bf16x8;
typedef __attribute__((ext_vector_type(4))) float f32x4;

__device__ __forceinline__ float bf2f(u32 u) { return __uint_as_float(u << 16); }
__device__ __forceinline__ u32 f2bfbits(float x) {          // RNE f32->bf16
    u32 u = __float_as_uint(x);
    return (u + 0x7FFFu + ((u >> 16) & 1u)) >> 16;
}
__device__ __forceinline__ float lrelu(float s) { return s > 0.f ? s : ALPHA * s; }

template <bool BF16>
__device__ __forceinline__ float ld(const void* p, size_t idx) {
    if constexpr (BF16) return bf2f(((const u16*)p)[idx]);
    else                return ((const float*)p)[idx];
}

// ---------------------------------------------------------------------------
// Kernel 0: dtype detect. adj[0,0] == 1.0 (self loop) always.
//   fp32: first word 0x3F800000 -> low16 == 0x0000 ; bf16: low16 == 0x3F80
// ---------------------------------------------------------------------------
__global__ void gat_detect_kernel(const unsigned* __restrict__ adj_words,
                                  int* __restrict__ flag) {
    *flag = ((adj_words[0] & 0xFFFFu) == 0x3F80u) ? 1 : 0;
}

// ---------------------------------------------------------------------------
// Kernel 1: Wh = h @ W. 4 rows per wave (register-blocked: W read once per
// 4 rows), 16 rows per block. Emits WhT [64][8192] bf16 scratch, src/dst fp32.
// ---------------------------------------------------------------------------
template <bool BF16>
__device__ __forceinline__ void wh4_impl(
    const void* __restrict__ h, const void* __restrict__ W,
    const void* __restrict__ a, float* __restrict__ src,
    float* __restrict__ dst, int i0, int lane, float* accv)
{
    float acc0 = 0.f, acc1 = 0.f, acc2 = 0.f, acc3 = 0.f;
#pragma unroll 8
    for (int k = 0; k < IN_F; ++k) {
        float wv = ld<BF16>(W, (size_t)k * OUT_F + lane);   // coalesced
        float h0 = ld<BF16>(h, (size_t)(i0 + 0) * IN_F + k);  // wave-uniform
        float h1 = ld<BF16>(h, (size_t)(i0 + 1) * IN_F + k);
        float h2 = ld<BF16>(h, (size_t)(i0 + 2) * IN_F + k);
        float h3 = ld<BF16>(h, (size_t)(i0 + 3) * IN_F + k);
        acc0 = fmaf(h0, wv, acc0);
        acc1 = fmaf(h1, wv, acc1);
        acc2 = fmaf(h2, wv, acc2);
        acc3 = fmaf(h3, wv, acc3);
    }
    float av = ld<BF16>(a, lane);
    float bv = ld<BF16>(a, OUT_F + lane);
    float accs[4] = {acc0, acc1, acc2, acc3};
#pragma unroll
    for (int r = 0; r < 4; ++r) {
        float ps = accs[r] * av, pd = accs[r] * bv;
#pragma unroll
        for (int off = 32; off > 0; off >>= 1) {
            ps += __shfl_xor(ps, off, 64);
            pd += __shfl_xor(pd, off, 64);
        }
        if (lane == 0) { src[i0 + r] = ps; dst[i0 + r] = pd; }
        accv[r] = accs[r];
    }
}

__global__ __launch_bounds__(256) void gat_wh_kernel(
    const void* __restrict__ h, const void* __restrict__ W,
    const void* __restrict__ a, const int* __restrict__ flag,
    u16* __restrict__ WhT, float* __restrict__ src, float* __restrict__ dst)
{
    __shared__ float accs[16][OUT_F];
    const int tid = threadIdx.x, wave = tid >> 6, lane = tid & 63;
    const int i0 = blockIdx.x * 16 + wave * 4;
    float av[4];
    if (*flag) wh4_impl<true >(h, W, a, src, dst, i0, lane, av);
    else       wh4_impl<false>(h, W, a, src, dst, i0, lane, av);
#pragma unroll
    for (int r = 0; r < 4; ++r) accs[wave * 4 + r][lane] = av[r];
    __syncthreads();
    if (tid < OUT_F) {                    // WhT[f][i0..i0+15], bf16 scratch
        u32 w[8];
#pragma unroll
        for (int e = 0; e < 8; ++e) {
            u32 lo = f2bfbits(accs[2 * e][tid]);
            u32 hi = f2bfbits(accs[2 * e + 1][tid]);
            w[e] = lo | (hi << 16);
        }
        u16* dstp = WhT + (size_t)tid * N_NODES + blockIdx.x * 16;
        *(uint4*)dstp       = *(uint4*)&w[0];
        *(uint4*)(dstp + 8) = *(uint4*)&w[4];
    }
}

// ---------------------------------------------------------------------------
// adj -> 16-bit nonzero mask for this thread's 16 columns of tile t.
// ---------------------------------------------------------------------------
template <bool BF16>
__device__ __forceinline__ u32 adj_mask16(const void* adjrow_base, int t)
{
    u32 msk = 0;
    if constexpr (BF16) {
        const uint4* p = (const uint4*)((const u16*)adjrow_base + t * 64);
        uint4 a0 = p[0], a1 = p[1];
        u32 aw[8] = {a0.x, a0.y, a0.z, a0.w, a1.x, a1.y, a1.z, a1.w};
#pragma unroll
        for (int e = 0; e < 8; ++e) {
            if (aw[e] & 0xFFFFu) msk |= (1u << (2 * e));
            if (aw[e] >> 16)     msk |= (1u << (2 * e + 1));
        }
    } else {
        const uint4* p = (const uint4*)((const float*)adjrow_base + t * 64);
        uint4 a0 = p[0], a1 = p[1], a2 = p[2], a3 = p[3];
        u32 aw[16] = {a0.x,a0.y,a0.z,a0.w, a1.x,a1.y,a1.z,a1.w,
                      a2.x,a2.y,a2.z,a2.w, a3.x,a3.y,a3.z,a3.w};
#pragma unroll
        for (int e = 0; e < 16; ++e)
            if (aw[e]) msk |= (1u << e);  // fp32 adj is exactly 0.0 / 1.0
    }
    return msk;
}

// ---------------------------------------------------------------------------
// Kernel 2: fused masked-softmax @ Wh via MFMA. Block = 64 rows x 1024 cols.
// Double-buffered LDS, register prefetch of tile t+1 during MFMA of tile t,
// ONE barrier per tile. Row-major (stride 72) LDS tiles; fragment
// A[m=lane&15][k=(lane>>4)*8+j] = contiguous ds_read_b128 (R6-proven).
// ---------------------------------------------------------------------------
__global__ __launch_bounds__(256, 4) void gat_attn_kernel(
    const void* __restrict__ adj, const u16* __restrict__ WhT,
    const float* __restrict__ src, const float* __restrict__ dst,
    const int* __restrict__ flag,
    float* __restrict__ O_part, float* __restrict__ l_part)
{
    __shared__ alignas(16) u16 Plds[2][64 * LDP];   // 2 x 9216 B
    __shared__ alignas(16) u16 Blds[2][64 * LDP];   // 2 x 9216 B

    const int tid = threadIdx.x, wave = tid >> 6, lane = tid & 63;
    const int r = tid >> 2, cq = tid & 3;           // producer row, 16-col chunk
    const int i0 = blockIdx.x * 64, c0 = blockIdx.y * COLS_PER;
    const int isbf = *flag;

    const float srow = src[i0 + r];
    const float m = lrelu(srow + MBIAS);            // upper bound of row max

    const void* adjrow = isbf
        ? (const void*)((const u16*)adj + (size_t)(i0 + r) * N_NODES + c0 + cq * 16)
        : (const void*)((const float*)adj + (size_t)(i0 + r) * N_NODES + c0 + cq * 16);
    const u16*    whtrow = WhT + (size_t)r * N_NODES + c0 + cq * 16;
    const float4* dstp   = (const float4*)(dst + c0 + cq * 16);

    const int mrow = (lane & 15);
    const int kq   = (lane >> 4) * 8;
    const int pw   = r * LDP + cq * 16;             // producer LDS slot

    f32x4 acc[4] = {{0,0,0,0},{0,0,0,0},{0,0,0,0},{0,0,0,0}};
    float lacc = 0.f;

    // tile-t prefetch registers
    uint4  pb0, pb1;
    u32    pmsk;
    float4 pd0, pd1, pd2, pd3;

#define LOAD_TILE(t)                                                      \
    do {                                                                  \
        pb0 = *(const uint4*)(whtrow + (t) * 64);                         \
        pb1 = *(const uint4*)(whtrow + (t) * 64 + 8);                     \
        pmsk = isbf ? adj_mask16<true >(adjrow, (t))                      \
                    : adj_mask16<false>(adjrow, (t));                     \
        pd0 = dstp[(t) * 16];     pd1 = dstp[(t) * 16 + 1];               \
        pd2 = dstp[(t) * 16 + 2]; pd3 = dstp[(t) * 16 + 3];               \
    } while (0)

#define STAGE_TILE(buf)                                                   \
    do {                                                                  \
        *(uint4*)&Blds[buf][pw]     = pb0;                                \
        *(uint4*)&Blds[buf][pw + 8] = pb1;                                \
        float dv[16] = {pd0.x,pd0.y,pd0.z,pd0.w, pd1.x,pd1.y,pd1.z,pd1.w, \
                        pd2.x,pd2.y,pd2.z,pd2.w, pd3.x,pd3.y,pd3.z,pd3.w};\
        u32 po[8];                                                        \
        _Pragma("unroll")                                                 \
        for (int e = 0; e < 8; ++e) {                                     \
            float s0 = lrelu(srow + dv[2 * e]);                           \
            float s1 = lrelu(srow + dv[2 * e + 1]);                       \
            float p0 = (pmsk & (1u << (2 * e)))     ? __expf(s0 - m) : 0.f;\
            float p1 = (pmsk & (1u << (2 * e + 1))) ? __expf(s1 - m) : 0.f;\
            u32 q0 = f2bfbits(p0), q1 = f2bfbits(p1);                     \
            lacc += bf2f(q0) + bf2f(q1);   /* l from ROUNDED P */         \
            po[e] = q0 | (q1 << 16);                                      \
        }                                                                 \
        *(uint4*)&Plds[buf][pw]     = *(uint4*)&po[0];                    \
        *(uint4*)&Plds[buf][pw + 8] = *(uint4*)&po[4];                    \
    } while (0)

    // prologue: tile 0 -> buf 0
    LOAD_TILE(0);
    STAGE_TILE(0);
    __syncthreads();

    for (int t = 0; t < NTILES; ++t) {
        const int cur = t & 1, nxt = cur ^ 1;
        if (t + 1 < NTILES) LOAD_TILE(t + 1);       // loads in flight over MFMA

#pragma unroll
        for (int ks = 0; ks < 2; ++ks) {
            bf16x8 avf = *(bf16x8*)&Plds[cur][(16 * wave + mrow) * LDP + ks * 32 + kq];
#pragma unroll
            for (int nt = 0; nt < 4; ++nt) {
                bf16x8 bvf = *(bf16x8*)&Blds[cur][(16 * nt + mrow) * LDP + ks * 32 + kq];
                acc[nt] = __builtin_amdgcn_mfma_f32_16x16x32_bf16(avf, bvf, acc[nt], 0, 0, 0);
            }
        }
        if (t + 1 < NTILES) STAGE_TILE(nxt);
        __syncthreads();                            // one barrier per tile
    }
#undef LOAD_TILE
#undef STAGE_TILE

    // partial l: sum over the 4 col-chunk threads of each row
    lacc += __shfl_xor(lacc, 1, 64);
    lacc += __shfl_xor(lacc, 2, 64);
    if (cq == 0) l_part[blockIdx.y * N_NODES + i0 + r] = lacc;

    // C/D layout: col = lane&15, row = (lane>>4)*4 + reg   [m89/m91 verified]
    float* Ob = O_part + (size_t)blockIdx.y * N_NODES * OUT_F;
#pragma unroll
    for (int nt = 0; nt < 4; ++nt)
#pragma unroll
        for (int reg = 0; reg < 4; ++reg) {
            int row = i0 + 16 * wave + (lane >> 4) * 4 + reg;
            int col = 16 * nt + (lane & 15);
            Ob[(size_t)row * OUT_F + col] = acc[nt][reg];
        }
}

// ---------------------------------------------------------------------------
// Kernel 3: out = elu( (sum_c O_c) / (sum_c l_c) ), store per dtype flag.
// ---------------------------------------------------------------------------
__global__ __launch_bounds__(256) void gat_reduce_kernel(
    const float* __restrict__ O_part, const float* __restrict__ l_part,
    const int* __restrict__ flag, void* __restrict__ out)
{
    int gid = blockIdx.x * 256 + threadIdx.x;
    int i = gid >> 6;
    float O = 0.f, L = 0.f;
#pragma unroll
    for (int c = 0; c < CSPL; ++c) {
        O += O_part[(size_t)c * N_NODES * OUT_F + gid];
        L += l_part[c * N_NODES + i];
    }
    float hp = O / L;
    float o = hp > 0.f ? hp : expm1f(hp);           // elu alpha=1
    if (*flag) ((u16*)out)[gid] = (u16)f2bfbits(o);
    else       ((float*)out)[gid] = o;
}

// ---------------------------------------------------------------------------
extern "C" void kernel_launch(void* const* d_in, const int* in_sizes, int n_in,
                              void* d_out, int out_size, void* d_ws, size_t ws_size,
                              hipStream_t stream)
{
    const void* h   = d_in[0];
    const void* adj = d_in[1];
    const void* W   = d_in[2];
    const void* a   = d_in[3];

    char* ws = (char*)d_ws;
    u16*   WhT    = (u16*)ws;                                   // 1 MB
    float* src    = (float*)(ws + (1u << 20));                  // 32 KB
    float* dst    = (float*)(ws + (1u << 20) + 32768);          // 32 KB
    int*   flag   = (int*)  (ws + (1u << 20) + 65536);
    float* O_part = (float*)(ws + (2u << 20));                  // 16 MB (8 splits)
    float* l_part = (float*)(ws + (18u << 20));                 // 256 KB

    gat_detect_kernel<<<1, 1, 0, stream>>>((const unsigned*)adj, flag);
    gat_wh_kernel<<<N_NODES / 16, 256, 0, stream>>>(h, W, a, flag, WhT, src, dst);
    dim3 grid(N_NODES / 64, CSPL);
    gat_attn_kernel<<<grid, 256, 0, stream>>>(adj, WhT, src, dst, flag, O_part, l_part);
    gat_reduce_kernel<<<N_NODES * OUT_F / 256, 256, 0, stream>>>(O_part, l_part, flag, d_out);
}

// Round 8
// 441.164 us; speedup vs baseline: 1.0023x; 1.0023x over previous
//
#include <hip/hip_runtime.h>
#include <hip/hip_bf16.h>

#define N_NODES 8192
#define IN_F    256
#define OUT_F   64
#define ALPHA   0.3f
#define MBIAS   20.0f            // >= max dst_j; softmax exact after l-division
#define CSPL    8                // column splits
#define COLS_PER (N_NODES / CSPL)    // 1024
#define NTILES  (COLS_PER / 64)      // 16
#define ROWS    32               // rows per attn block
#define LDP     72               // padded LDS row stride (u16): 64 + 8, 16B-aligned

typedef unsigned short u16;
typedef unsigned int   u32;
typedef __attribute__((ext_vector_type(8))) short bf16x8;
typedef __attribute__((ext_vector_type(4))) float f32x4;

__device__ __forceinline__ float bf2f(u32 u) { return __uint_as_float(u << 16); }
__device__ __forceinline__ u32 f2bfbits(float x) {          // RNE f32->bf16
    u32 u = __float_as_uint(x);
    return (u + 0x7FFFu + ((u >> 16) & 1u)) >> 16;
}
__device__ __forceinline__ float lrelu(float s) { return s > 0.f ? s : ALPHA * s; }

// dtype probe: adj[0,0] == 1.0 always. bf16 -> low16 of first word = 0x3F80.
__device__ __forceinline__ int detect_bf16(const void* adj) {
    return ((((const u32*)adj)[0] & 0xFFFFu) == 0x3F80u) ? 1 : 0;
}

template <bool BF16>
__device__ __forceinline__ float ld(const void* p, size_t idx) {
    if constexpr (BF16) return bf2f(((const u16*)p)[idx]);
    else                return ((const float*)p)[idx];
}

// ---------------------------------------------------------------------------
// Kernel 1: Wh = h @ W. 4 rows per wave (W read once per 4 rows), 16 rows
// per block. Emits WhT [64][8192] bf16 scratch, src/dst fp32.
// ---------------------------------------------------------------------------
template <bool BF16>
__device__ __forceinline__ void wh4_impl(
    const void* __restrict__ h, const void* __restrict__ W,
    const void* __restrict__ a, float* __restrict__ src,
    float* __restrict__ dst, int i0, int lane, float* accv)
{
    float acc0 = 0.f, acc1 = 0.f, acc2 = 0.f, acc3 = 0.f;
#pragma unroll 8
    for (int k = 0; k < IN_F; ++k) {
        float wv = ld<BF16>(W, (size_t)k * OUT_F + lane);      // coalesced
        float h0 = ld<BF16>(h, (size_t)(i0 + 0) * IN_F + k);   // wave-uniform
        float h1 = ld<BF16>(h, (size_t)(i0 + 1) * IN_F + k);
        float h2 = ld<BF16>(h, (size_t)(i0 + 2) * IN_F + k);
        float h3 = ld<BF16>(h, (size_t)(i0 + 3) * IN_F + k);
        acc0 = fmaf(h0, wv, acc0);
        acc1 = fmaf(h1, wv, acc1);
        acc2 = fmaf(h2, wv, acc2);
        acc3 = fmaf(h3, wv, acc3);
    }
    float av = ld<BF16>(a, lane);
    float bv = ld<BF16>(a, OUT_F + lane);
    float accs[4] = {acc0, acc1, acc2, acc3};
#pragma unroll
    for (int r = 0; r < 4; ++r) {
        float ps = accs[r] * av, pd = accs[r] * bv;
#pragma unroll
        for (int off = 32; off > 0; off >>= 1) {
            ps += __shfl_xor(ps, off, 64);
            pd += __shfl_xor(pd, off, 64);
        }
        if (lane == 0) { src[i0 + r] = ps; dst[i0 + r] = pd; }
        accv[r] = accs[r];
    }
}

__global__ __launch_bounds__(256) void gat_wh_kernel(
    const void* __restrict__ h, const void* __restrict__ W,
    const void* __restrict__ a, const void* __restrict__ adj,
    u16* __restrict__ WhT, float* __restrict__ src, float* __restrict__ dst)
{
    __shared__ float accs[16][OUT_F];
    const int tid = threadIdx.x, wave = tid >> 6, lane = tid & 63;
    const int i0 = blockIdx.x * 16 + wave * 4;
    float av[4];
    if (detect_bf16(adj)) wh4_impl<true >(h, W, a, src, dst, i0, lane, av);
    else                  wh4_impl<false>(h, W, a, src, dst, i0, lane, av);
#pragma unroll
    for (int r = 0; r < 4; ++r) accs[wave * 4 + r][lane] = av[r];
    __syncthreads();
    if (tid < OUT_F) {                    // WhT[f][i0..i0+15], bf16 scratch
        u32 w[8];
#pragma unroll
        for (int e = 0; e < 8; ++e) {
            u32 lo = f2bfbits(accs[2 * e][tid]);
            u32 hi = f2bfbits(accs[2 * e + 1][tid]);
            w[e] = lo | (hi << 16);
        }
        u16* dstp = WhT + (size_t)tid * N_NODES + blockIdx.x * 16;
        *(uint4*)dstp       = *(uint4*)&w[0];
        *(uint4*)(dstp + 8) = *(uint4*)&w[4];
    }
}

// ---------------------------------------------------------------------------
// Kernel 2: fused masked-softmax @ Wh via MFMA. Block = 32 rows x 1024 cols,
// grid 256x8 = 2048 blocks (8 blocks/CU target for latency hiding).
// Per 32x64 tile: P = adj ? exp(lrelu(src+dst)-m) : 0, row-major (stride 72)
// LDS; B = WhT 64x64 tile likewise. Fragment A[m=lane&15][k=(lane>>4)*8+j]
// is one contiguous ds_read_b128 (R6-proven). Two barriers per tile.
// Each wave: m-tile (wave&1), 2 n-tiles (wave>>1) -> 4 MFMAs, 8 acc VGPRs.
// ---------------------------------------------------------------------------
__global__ __launch_bounds__(256, 8) void gat_attn_kernel(
    const void* __restrict__ adj, const u16* __restrict__ WhT,
    const float* __restrict__ src, const float* __restrict__ dst,
    float* __restrict__ O_part, float* __restrict__ l_part)
{
    __shared__ alignas(16) u16 Plds[ROWS * LDP];   // 4608 B
    __shared__ alignas(16) u16 Blds[64 * LDP];     // 9216 B

    const int tid = threadIdx.x, wave = tid >> 6, lane = tid & 63;
    const int r  = tid >> 3, cq = tid & 7;         // P producer: row, 8-col chunk
    const int br = tid >> 2, bq = tid & 3;         // B producer: feat, 16-col chunk
    const int i0 = blockIdx.x * ROWS, c0 = blockIdx.y * COLS_PER;
    const int isbf = detect_bf16(adj);

    const float srow = src[i0 + r];
    const float m = lrelu(srow + MBIAS);           // upper bound of row max

    const u16*    whtrow = WhT + (size_t)br * N_NODES + c0 + bq * 16;
    const float4* dstp   = (const float4*)(dst + c0 + cq * 8);
    const u16*    adj16  = (const u16*)adj   + (size_t)(i0 + r) * N_NODES + c0 + cq * 8;
    const float*  adj32  = (const float*)adj + (size_t)(i0 + r) * N_NODES + c0 + cq * 8;

    const int mw = wave & 1, nw = wave >> 1;
    const int mrow = lane & 15, kq = (lane >> 4) * 8;

    f32x4 acc[2] = {{0,0,0,0},{0,0,0,0}};
    float lacc = 0.f;

    for (int t = 0; t < NTILES; ++t) {
        // --- stage B tile (64 feats x 64 cols) ---
        uint4 b0 = *(const uint4*)(whtrow + t * 64);
        uint4 b1 = *(const uint4*)(whtrow + t * 64 + 8);
        *(uint4*)&Blds[br * LDP + bq * 16]     = b0;
        *(uint4*)&Blds[br * LDP + bq * 16 + 8] = b1;

        // --- stage P tile (32 rows x 64 cols), 8 cols per thread ---
        u32 msk = 0;
        if (isbf) {
            uint4 av = *(const uint4*)(adj16 + t * 64);
            u32 aw[4] = {av.x, av.y, av.z, av.w};
#pragma unroll
            for (int e = 0; e < 4; ++e) {
                if (aw[e] & 0xFFFFu) msk |= (1u << (2 * e));
                if (aw[e] >> 16)     msk |= (1u << (2 * e + 1));
            }
        } else {
            uint4 a0 = *(const uint4*)(adj32 + t * 64);
            uint4 a1 = *(const uint4*)(adj32 + t * 64 + 4);
            u32 aw[8] = {a0.x,a0.y,a0.z,a0.w, a1.x,a1.y,a1.z,a1.w};
#pragma unroll
            for (int e = 0; e < 8; ++e)
                if (aw[e]) msk |= (1u << e);       // fp32 adj is exactly 0/1
        }
        float4 d0 = dstp[t * 16], d1 = dstp[t * 16 + 1];
        float dv[8] = {d0.x,d0.y,d0.z,d0.w, d1.x,d1.y,d1.z,d1.w};
        u32 po[4];
#pragma unroll
        for (int e = 0; e < 4; ++e) {
            float s0 = lrelu(srow + dv[2 * e]);
            float s1 = lrelu(srow + dv[2 * e + 1]);
            float p0 = (msk & (1u << (2 * e)))     ? __expf(s0 - m) : 0.f;
            float p1 = (msk & (1u << (2 * e + 1))) ? __expf(s1 - m) : 0.f;
            u32 q0 = f2bfbits(p0), q1 = f2bfbits(p1);
            lacc += bf2f(q0) + bf2f(q1);           // l from ROUNDED P
            po[e] = q0 | (q1 << 16);
        }
        *(uint4*)&Plds[r * LDP + cq * 8] = *(uint4*)&po[0];

        __syncthreads();

#pragma unroll
        for (int ks = 0; ks < 2; ++ks) {
            bf16x8 avf = *(bf16x8*)&Plds[(16 * mw + mrow) * LDP + ks * 32 + kq];
#pragma unroll
            for (int nt2 = 0; nt2 < 2; ++nt2) {
                int nt = nw * 2 + nt2;
                bf16x8 bvf = *(bf16x8*)&Blds[(16 * nt + mrow) * LDP + ks * 32 + kq];
                acc[nt2] = __builtin_amdgcn_mfma_f32_16x16x32_bf16(avf, bvf, acc[nt2], 0, 0, 0);
            }
        }
        __syncthreads();
    }

    // partial l: sum over the 8 col-chunk threads of each row (consecutive lanes)
    lacc += __shfl_xor(lacc, 1, 64);
    lacc += __shfl_xor(lacc, 2, 64);
    lacc += __shfl_xor(lacc, 4, 64);
    if (cq == 0) l_part[blockIdx.y * N_NODES + i0 + r] = lacc;

    // C/D layout: col = lane&15, row = (lane>>4)*4 + reg   [m89/m91 verified]
    float* Ob = O_part + (size_t)blockIdx.y * N_NODES * OUT_F;
#pragma unroll
    for (int nt2 = 0; nt2 < 2; ++nt2) {
        int nt = nw * 2 + nt2;
#pragma unroll
        for (int reg = 0; reg < 4; ++reg) {
            int row = i0 + 16 * mw + (lane >> 4) * 4 + reg;
            int col = 16 * nt + (lane & 15);
            Ob[(size_t)row * OUT_F + col] = acc[nt2][reg];
        }
    }
}

// ---------------------------------------------------------------------------
// Kernel 3: out = elu( (sum_c O_c) / (sum_c l_c) ), store per dtype.
// ---------------------------------------------------------------------------
__global__ __launch_bounds__(256) void gat_reduce_kernel(
    const float* __restrict__ O_part, const float* __restrict__ l_part,
    const void* __restrict__ adj, void* __restrict__ out)
{
    int gid = blockIdx.x * 256 + threadIdx.x;
    int i = gid >> 6;
    float O = 0.f, L = 0.f;
#pragma unroll
    for (int c = 0; c < CSPL; ++c) {
        O += O_part[(size_t)c * N_NODES * OUT_F + gid];
        L += l_part[c * N_NODES + i];
    }
    float hp = O / L;
    float o = hp > 0.f ? hp : expm1f(hp);          // elu alpha=1
    if (detect_bf16(adj)) ((u16*)out)[gid] = (u16)f2bfbits(o);
    else                  ((float*)out)[gid] = o;
}

// ---------------------------------------------------------------------------
extern "C" void kernel_launch(void* const* d_in, const int* in_sizes, int n_in,
                              void* d_out, int out_size, void* d_ws, size_t ws_size,
                              hipStream_t stream)
{
    const void* h   = d_in[0];
    const void* adj = d_in[1];
    const void* W   = d_in[2];
    const void* a   = d_in[3];

    char* ws = (char*)d_ws;
    u16*   WhT    = (u16*)ws;                                   // 1 MB
    float* src    = (float*)(ws + (1u << 20));                  // 32 KB
    float* dst    = (float*)(ws + (1u << 20) + 32768);          // 32 KB
    float* O_part = (float*)(ws + (2u << 20));                  // 16 MB (8 splits)
    float* l_part = (float*)(ws + (18u << 20));                 // 256 KB

    gat_wh_kernel<<<N_NODES / 16, 256, 0, stream>>>(h, W, a, adj, WhT, src, dst);
    dim3 grid(N_NODES / ROWS, CSPL);
    gat_attn_kernel<<<grid, 256, 0, stream>>>(adj, WhT, src, dst, O_part, l_part);
    gat_reduce_kernel<<<N_NODES * OUT_F / 256, 256, 0, stream>>>(O_part, l_part, adj, d_out);
}

// Round 9
// 426.846 us; speedup vs baseline: 1.0360x; 1.0335x over previous
//
#include <hip/hip_runtime.h>
#include <hip/hip_bf16.h>

#define N_NODES 8192
#define IN_F    256
#define OUT_F   64
#define ALPHA   0.3f
#define MBIAS   20.0f            // >= max dst_j; softmax exact after l-division
#define CSPL    8                // column splits
#define COLS_PER (N_NODES / CSPL)    // 1024
#define NTILES  (COLS_PER / 64)      // 16
#define ROWS    32               // rows per attn block
#define LDP     72               // padded LDS row stride (u16): 64 + 8
#define MROW    136              // mask LDS row stride (bytes): 128 + 8

typedef unsigned short u16;
typedef unsigned int   u32;
typedef unsigned long long u64;
typedef __attribute__((ext_vector_type(8))) short bf16x8;
typedef __attribute__((ext_vector_type(4))) float f32x4;

__device__ __forceinline__ float bf2f(u32 u) { return __uint_as_float(u << 16); }
__device__ __forceinline__ u32 f2bfbits(float x) {          // RNE f32->bf16
    u32 u = __float_as_uint(x);
    return (u + 0x7FFFu + ((u >> 16) & 1u)) >> 16;
}
__device__ __forceinline__ float lrelu(float s) { return s > 0.f ? s : ALPHA * s; }

// dtype probe: adj[0,0] == 1.0 always. bf16 -> low16 of first word = 0x3F80.
__device__ __forceinline__ int detect_bf16(const void* adj) {
    return ((((const u32*)adj)[0] & 0xFFFFu) == 0x3F80u) ? 1 : 0;
}

template <bool BF16>
__device__ __forceinline__ float ld(const void* p, size_t idx) {
    if constexpr (BF16) return bf2f(((const u16*)p)[idx]);
    else                return ((const float*)p)[idx];
}

// ---------------------------------------------------------------------------
// Kernel 0: adj -> bitmask (1 bit/elem, natural order). Barrier-free stream.
// Per wave-chunk: 256 consecutive elems; lane-coalesced loads; 4 ballots
// give 4 u64 words in natural bit order (ballot bit l = lane l = col base+64q+l).
// ---------------------------------------------------------------------------
__global__ __launch_bounds__(256) void gat_mask_kernel(
    const void* __restrict__ adj, u64* __restrict__ mask64)
{
    const int lane = threadIdx.x & 63;
    const int wgid = blockIdx.x * 4 + (threadIdx.x >> 6);
    const int NW   = 2048 * 4;
    const int C    = (N_NODES / 256) * N_NODES;   // 262144 chunks of 256 elems

    if (detect_bf16(adj)) {
        const u16* base = (const u16*)adj;
        for (int c = wgid; c < C; c += NW) {
            const u16* p = base + (size_t)c * 256;
            u64 b0 = __ballot(p[lane]       != 0);
            u64 b1 = __ballot(p[64  + lane] != 0);
            u64 b2 = __ballot(p[128 + lane] != 0);
            u64 b3 = __ballot(p[192 + lane] != 0);
            u64 v = (lane == 0) ? b0 : (lane == 1) ? b1 : (lane == 2) ? b2 : b3;
            if (lane < 4) mask64[(size_t)c * 4 + lane] = v;
        }
    } else {
        const float* base = (const float*)adj;
        for (int c = wgid; c < C; c += NW) {
            const float* p = base + (size_t)c * 256;
            u64 b0 = __ballot(p[lane]       != 0.f);
            u64 b1 = __ballot(p[64  + lane] != 0.f);
            u64 b2 = __ballot(p[128 + lane] != 0.f);
            u64 b3 = __ballot(p[192 + lane] != 0.f);
            u64 v = (lane == 0) ? b0 : (lane == 1) ? b1 : (lane == 2) ? b2 : b3;
            if (lane < 4) mask64[(size_t)c * 4 + lane] = v;
        }
    }
}

// ---------------------------------------------------------------------------
// Kernel 1: Wh = h @ W. 4 rows per wave (W read once per 4 rows), 16 rows
// per block. Emits WhT [64][8192] bf16 scratch, src/dst fp32. (R8-proven)
// ---------------------------------------------------------------------------
template <bool BF16>
__device__ __forceinline__ void wh4_impl(
    const void* __restrict__ h, const void* __restrict__ W,
    const void* __restrict__ a, float* __restrict__ src,
    float* __restrict__ dst, int i0, int lane, float* accv)
{
    float acc0 = 0.f, acc1 = 0.f, acc2 = 0.f, acc3 = 0.f;
#pragma unroll 8
    for (int k = 0; k < IN_F; ++k) {
        float wv = ld<BF16>(W, (size_t)k * OUT_F + lane);      // coalesced
        float h0 = ld<BF16>(h, (size_t)(i0 + 0) * IN_F + k);   // wave-uniform
        float h1 = ld<BF16>(h, (size_t)(i0 + 1) * IN_F + k);
        float h2 = ld<BF16>(h, (size_t)(i0 + 2) * IN_F + k);
        float h3 = ld<BF16>(h, (size_t)(i0 + 3) * IN_F + k);
        acc0 = fmaf(h0, wv, acc0);
        acc1 = fmaf(h1, wv, acc1);
        acc2 = fmaf(h2, wv, acc2);
        acc3 = fmaf(h3, wv, acc3);
    }
    float av = ld<BF16>(a, lane);
    float bv = ld<BF16>(a, OUT_F + lane);
    float accs[4] = {acc0, acc1, acc2, acc3};
#pragma unroll
    for (int r = 0; r < 4; ++r) {
        float ps = accs[r] * av, pd = accs[r] * bv;
#pragma unroll
        for (int off = 32; off > 0; off >>= 1) {
            ps += __shfl_xor(ps, off, 64);
            pd += __shfl_xor(pd, off, 64);
        }
        if (lane == 0) { src[i0 + r] = ps; dst[i0 + r] = pd; }
        accv[r] = accs[r];
    }
}

__global__ __launch_bounds__(256) void gat_wh_kernel(
    const void* __restrict__ h, const void* __restrict__ W,
    const void* __restrict__ a, const void* __restrict__ adj,
    u16* __restrict__ WhT, float* __restrict__ src, float* __restrict__ dst)
{
    __shared__ float accs[16][OUT_F];
    const int tid = threadIdx.x, wave = tid >> 6, lane = tid & 63;
    const int i0 = blockIdx.x * 16 + wave * 4;
    float av[4];
    if (detect_bf16(adj)) wh4_impl<true >(h, W, a, src, dst, i0, lane, av);
    else                  wh4_impl<false>(h, W, a, src, dst, i0, lane, av);
#pragma unroll
    for (int r = 0; r < 4; ++r) accs[wave * 4 + r][lane] = av[r];
    __syncthreads();
    if (tid < OUT_F) {                    // WhT[f][i0..i0+15], bf16 scratch
        u32 w[8];
#pragma unroll
        for (int e = 0; e < 8; ++e) {
            u32 lo = f2bfbits(accs[2 * e][tid]);
            u32 hi = f2bfbits(accs[2 * e + 1][tid]);
            w[e] = lo | (hi << 16);
        }
        u16* dstp = WhT + (size_t)tid * N_NODES + blockIdx.x * 16;
        *(uint4*)dstp       = *(uint4*)&w[0];
        *(uint4*)(dstp + 8) = *(uint4*)&w[4];
    }
}

// ---------------------------------------------------------------------------
// Kernel 2: fused masked-softmax @ Wh via MFMA. Block = 32 rows x 1024 cols.
// Zero HBM in the K-loop: adj replaced by an LDS-staged 4 KB bitmask window;
// WhT (1 MB) and dst (32 KB) are L2-resident. Row-major (stride 72) LDS
// tiles; fragment A[m=lane&15][k=(lane>>4)*8+j] = one ds_read_b128.
// ---------------------------------------------------------------------------
__global__ __launch_bounds__(256, 4) void gat_attn_kernel(
    const u64* __restrict__ mask64, const u16* __restrict__ WhT,
    const float* __restrict__ src, const float* __restrict__ dst,
    float* __restrict__ O_part, float* __restrict__ l_part)
{
    __shared__ alignas(16) u16 Plds[ROWS * LDP];          // 4608 B
    __shared__ alignas(16) u16 Blds[64 * LDP];            // 9216 B
    __shared__ alignas(16) unsigned char Mlds[ROWS * MROW]; // 4352 B

    const int tid = threadIdx.x, wave = tid >> 6, lane = tid & 63;
    const int r  = tid >> 3, cq = tid & 7;        // P producer: row, 8-col chunk
    const int br = tid >> 2, bq = tid & 3;        // B producer: feat, 16-col chunk
    const int i0 = blockIdx.x * ROWS, c0 = blockIdx.y * COLS_PER;

    // stage mask window: 32 rows x 128 B (uint4 per thread, coalesced)
    {
        const unsigned char* mb = (const unsigned char*)mask64;
        uint4 v = *(const uint4*)(mb + (size_t)(i0 + (tid >> 3)) * (N_NODES / 8)
                                     + (c0 >> 3) + (tid & 7) * 16);
        *(uint4*)&Mlds[(tid >> 3) * MROW + (tid & 7) * 16] = v;
    }

    const float srow = src[i0 + r];
    const float m = lrelu(srow + MBIAS);          // upper bound of row max

    const u16*    whtrow = WhT + (size_t)br * N_NODES + c0 + bq * 16;
    const float4* dstp   = (const float4*)(dst + c0 + cq * 8);

    const int mw = wave & 1, nw = wave >> 1;
    const int mrow = lane & 15, kq = (lane >> 4) * 8;

    f32x4 acc[2] = {{0,0,0,0},{0,0,0,0}};
    float lacc = 0.f;

    __syncthreads();                              // mask window ready

    for (int t = 0; t < NTILES; ++t) {
        // stage B tile (64 feats x 64 cols) from L2-resident WhT
        uint4 b0 = *(const uint4*)(whtrow + t * 64);
        uint4 b1 = *(const uint4*)(whtrow + t * 64 + 8);
        *(uint4*)&Blds[br * LDP + bq * 16]     = b0;
        *(uint4*)&Blds[br * LDP + bq * 16 + 8] = b1;

        // stage P tile (32 rows x 64 cols), 8 cols/thread; mask byte from LDS
        u32 msk = Mlds[r * MROW + t * 8 + cq];
        float4 d0 = dstp[t * 16], d1 = dstp[t * 16 + 1];
        float dv[8] = {d0.x,d0.y,d0.z,d0.w, d1.x,d1.y,d1.z,d1.w};
        u32 po[4];
#pragma unroll
        for (int e = 0; e < 4; ++e) {
            float s0 = lrelu(srow + dv[2 * e]);
            float s1 = lrelu(srow + dv[2 * e + 1]);
            float p0 = (msk & (1u << (2 * e)))     ? __expf(s0 - m) : 0.f;
            float p1 = (msk & (1u << (2 * e + 1))) ? __expf(s1 - m) : 0.f;
            u32 q0 = f2bfbits(p0), q1 = f2bfbits(p1);
            lacc += bf2f(q0) + bf2f(q1);          // l from ROUNDED P
            po[e] = q0 | (q1 << 16);
        }
        *(uint4*)&Plds[r * LDP + cq * 8] = *(uint4*)&po[0];

        __syncthreads();

#pragma unroll
        for (int ks = 0; ks < 2; ++ks) {
            bf16x8 avf = *(bf16x8*)&Plds[(16 * mw + mrow) * LDP + ks * 32 + kq];
#pragma unroll
            for (int nt2 = 0; nt2 < 2; ++nt2) {
                int nt = nw * 2 + nt2;
                bf16x8 bvf = *(bf16x8*)&Blds[(16 * nt + mrow) * LDP + ks * 32 + kq];
                acc[nt2] = __builtin_amdgcn_mfma_f32_16x16x32_bf16(avf, bvf, acc[nt2], 0, 0, 0);
            }
        }
        __syncthreads();
    }

    // partial l: sum over the 8 col-chunk threads of each row
    lacc += __shfl_xor(lacc, 1, 64);
    lacc += __shfl_xor(lacc, 2, 64);
    lacc += __shfl_xor(lacc, 4, 64);
    if (cq == 0) l_part[blockIdx.y * N_NODES + i0 + r] = lacc;

    // C/D layout: col = lane&15, row = (lane>>4)*4 + reg   [m89/m91 verified]
    float* Ob = O_part + (size_t)blockIdx.y * N_NODES * OUT_F;
#pragma unroll
    for (int nt2 = 0; nt2 < 2; ++nt2) {
        int nt = nw * 2 + nt2;
#pragma unroll
        for (int reg = 0; reg < 4; ++reg) {
            int row = i0 + 16 * mw + (lane >> 4) * 4 + reg;
            int col = 16 * nt + (lane & 15);
            Ob[(size_t)row * OUT_F + col] = acc[nt2][reg];
        }
    }
}

// ---------------------------------------------------------------------------
// Kernel 3: out = elu( (sum_c O_c) / (sum_c l_c) ), store per dtype.
// ---------------------------------------------------------------------------
__global__ __launch_bounds__(256) void gat_reduce_kernel(
    const float* __restrict__ O_part, const float* __restrict__ l_part,
    const void* __restrict__ adj, void* __restrict__ out)
{
    int gid = blockIdx.x * 256 + threadIdx.x;
    int i = gid >> 6;
    float O = 0.f, L = 0.f;
#pragma unroll
    for (int c = 0; c < CSPL; ++c) {
        O += O_part[(size_t)c * N_NODES * OUT_F + gid];
        L += l_part[c * N_NODES + i];
    }
    float hp = O / L;
    float o = hp > 0.f ? hp : expm1f(hp);         // elu alpha=1
    if (detect_bf16(adj)) ((u16*)out)[gid] = (u16)f2bfbits(o);
    else                  ((float*)out)[gid] = o;
}

// ---------------------------------------------------------------------------
extern "C" void kernel_launch(void* const* d_in, const int* in_sizes, int n_in,
                              void* d_out, int out_size, void* d_ws, size_t ws_size,
                              hipStream_t stream)
{
    const void* h   = d_in[0];
    const void* adj = d_in[1];
    const void* W   = d_in[2];
    const void* a   = d_in[3];

    char* ws = (char*)d_ws;
    u16*   WhT    = (u16*)ws;                                   // 1 MB
    float* src    = (float*)(ws + (1u << 20));                  // 32 KB
    float* dst    = (float*)(ws + (1u << 20) + 32768);          // 32 KB
    u64*   mask64 = (u64*)  (ws + (2u << 20));                  // 8 MB
    float* O_part = (float*)(ws + (16u << 20));                 // 16 MB (8 splits)
    float* l_part = (float*)(ws + (32u << 20));                 // 256 KB

    gat_mask_kernel<<<2048, 256, 0, stream>>>(adj, mask64);
    gat_wh_kernel<<<N_NODES / 16, 256, 0, stream>>>(h, W, a, adj, WhT, src, dst);
    dim3 grid(N_NODES / ROWS, CSPL);
    gat_attn_kernel<<<grid, 256, 0, stream>>>(mask64, WhT, src, dst, O_part, l_part);
    gat_reduce_kernel<<<N_NODES * OUT_F / 256, 256, 0, stream>>>(O_part, l_part, adj, d_out);
}

// Round 10
// 426.782 us; speedup vs baseline: 1.0361x; 1.0001x over previous
//
#include <hip/hip_runtime.h>
#include <hip/hip_bf16.h>

#define N_NODES 8192
#define IN_F    256
#define OUT_F   64
#define ALPHA   0.3f
#define MBIAS   20.0f            // >= max dst_j; softmax exact after l-division
#define CSPL    8                // column splits
#define COLS_PER (N_NODES / CSPL)    // 1024
#define NTILES  (COLS_PER / 64)      // 16
#define LDP     72               // padded LDS row stride (u16): 64 + 8
#define MROW    136              // mask LDS row stride (bytes): 128 + 8
#define WH_BLOCKS (N_NODES / 16)     // 512

typedef unsigned short u16;
typedef unsigned int   u32;
typedef unsigned long long u64;
typedef __attribute__((ext_vector_type(8))) short bf16x8;
typedef __attribute__((ext_vector_type(4))) float f32x4;

__device__ __forceinline__ float bf2f(u32 u) { return __uint_as_float(u << 16); }
__device__ __forceinline__ u32 f2bfbits(float x) {          // RNE f32->bf16
    u32 u = __float_as_uint(x);
    return (u + 0x7FFFu + ((u >> 16) & 1u)) >> 16;
}
__device__ __forceinline__ float lrelu(float s) { return s > 0.f ? s : ALPHA * s; }

// dtype probe: adj[0,0] == 1.0 always. bf16 -> low16 of first word = 0x3F80.
__device__ __forceinline__ int detect_bf16(const void* adj) {
    return ((((const u32*)adj)[0] & 0xFFFFu) == 0x3F80u) ? 1 : 0;
}

template <bool BF16>
__device__ __forceinline__ float ld(const void* p, size_t idx) {
    if constexpr (BF16) return bf2f(((const u16*)p)[idx]);
    else                return ((const float*)p)[idx];
}

// ---------------------------------------------------------------------------
// Kernel 1 (fused prep): blocks [0,512): Wh = h @ W  (R9-proven body);
// blocks [512,2560): adj -> bitmask stream (R9-proven body).
// ---------------------------------------------------------------------------
template <bool BF16>
__device__ __forceinline__ void wh4_impl(
    const void* __restrict__ h, const void* __restrict__ W,
    const void* __restrict__ a, float* __restrict__ src,
    float* __restrict__ dst, int i0, int lane, float* accv)
{
    float acc0 = 0.f, acc1 = 0.f, acc2 = 0.f, acc3 = 0.f;
#pragma unroll 8
    for (int k = 0; k < IN_F; ++k) {
        float wv = ld<BF16>(W, (size_t)k * OUT_F + lane);      // coalesced
        float h0 = ld<BF16>(h, (size_t)(i0 + 0) * IN_F + k);   // wave-uniform
        float h1 = ld<BF16>(h, (size_t)(i0 + 1) * IN_F + k);
        float h2 = ld<BF16>(h, (size_t)(i0 + 2) * IN_F + k);
        float h3 = ld<BF16>(h, (size_t)(i0 + 3) * IN_F + k);
        acc0 = fmaf(h0, wv, acc0);
        acc1 = fmaf(h1, wv, acc1);
        acc2 = fmaf(h2, wv, acc2);
        acc3 = fmaf(h3, wv, acc3);
    }
    float av = ld<BF16>(a, lane);
    float bv = ld<BF16>(a, OUT_F + lane);
    float accs[4] = {acc0, acc1, acc2, acc3};
#pragma unroll
    for (int r = 0; r < 4; ++r) {
        float ps = accs[r] * av, pd = accs[r] * bv;
#pragma unroll
        for (int off = 32; off > 0; off >>= 1) {
            ps += __shfl_xor(ps, off, 64);
            pd += __shfl_xor(pd, off, 64);
        }
        if (lane == 0) { src[i0 + r] = ps; dst[i0 + r] = pd; }
        accv[r] = accs[r];
    }
}

__global__ __launch_bounds__(256) void gat_prep_kernel(
    const void* __restrict__ h, const void* __restrict__ W,
    const void* __restrict__ a, const void* __restrict__ adj,
    u16* __restrict__ WhT, float* __restrict__ src, float* __restrict__ dst,
    u64* __restrict__ mask64)
{
    __shared__ float accs[16][OUT_F];
    const int tid = threadIdx.x, wave = tid >> 6, lane = tid & 63;
    const int isbf = detect_bf16(adj);

    if (blockIdx.x < WH_BLOCKS) {
        // ---------------- Wh part ----------------
        const int i0 = blockIdx.x * 16 + wave * 4;
        float av[4];
        if (isbf) wh4_impl<true >(h, W, a, src, dst, i0, lane, av);
        else      wh4_impl<false>(h, W, a, src, dst, i0, lane, av);
#pragma unroll
        for (int r = 0; r < 4; ++r) accs[wave * 4 + r][lane] = av[r];
        __syncthreads();
        if (tid < OUT_F) {                // WhT[f][i0..i0+15], bf16 scratch
            u32 w[8];
#pragma unroll
            for (int e = 0; e < 8; ++e) {
                u32 lo = f2bfbits(accs[2 * e][tid]);
                u32 hi = f2bfbits(accs[2 * e + 1][tid]);
                w[e] = lo | (hi << 16);
            }
            u16* dstp = WhT + (size_t)tid * N_NODES + blockIdx.x * 16;
            *(uint4*)dstp       = *(uint4*)&w[0];
            *(uint4*)(dstp + 8) = *(uint4*)&w[4];
        }
    } else {
        // ---------------- mask part ----------------
        const int wgid = (blockIdx.x - WH_BLOCKS) * 4 + wave;
        const int NW   = 2048 * 4;
        const int C    = (N_NODES / 256) * N_NODES;   // 262144 chunks
        if (isbf) {
            const u16* base = (const u16*)adj;
            for (int c = wgid; c < C; c += NW) {
                const u16* p = base + (size_t)c * 256;
                u64 b0 = __ballot(p[lane]       != 0);
                u64 b1 = __ballot(p[64  + lane] != 0);
                u64 b2 = __ballot(p[128 + lane] != 0);
                u64 b3 = __ballot(p[192 + lane] != 0);
                u64 v = (lane == 0) ? b0 : (lane == 1) ? b1 : (lane == 2) ? b2 : b3;
                if (lane < 4) mask64[(size_t)c * 4 + lane] = v;
            }
        } else {
            const float* base = (const float*)adj;
            for (int c = wgid; c < C; c += NW) {
                const float* p = base + (size_t)c * 256;
                u64 b0 = __ballot(p[lane]       != 0.f);
                u64 b1 = __ballot(p[64  + lane] != 0.f);
                u64 b2 = __ballot(p[128 + lane] != 0.f);
                u64 b3 = __ballot(p[192 + lane] != 0.f);
                u64 v = (lane == 0) ? b0 : (lane == 1) ? b1 : (lane == 2) ? b2 : b3;
                if (lane < 4) mask64[(size_t)c * 4 + lane] = v;
            }
        }
    }
}

// ---------------------------------------------------------------------------
// Kernel 2: fused masked-softmax @ Wh via MFMA. Block = 64 rows x 1024 cols,
// grid 128x8 = 1024 blocks (4/CU). Zero HBM in K-loop: mask window (8 KB)
// staged once in LDS; WhT/dst from L2/L3 with register prefetch of the next
// B-tile issued during MFMA. Row-major (stride 72) LDS tiles; fragment
// A[m=lane&15][k=(lane>>4)*8+j] = one contiguous ds_read_b128 (R6-proven).
// ---------------------------------------------------------------------------
__global__ __launch_bounds__(256, 4) void gat_attn_kernel(
    const u64* __restrict__ mask64, const u16* __restrict__ WhT,
    const float* __restrict__ src, const float* __restrict__ dst,
    float* __restrict__ O_part, float* __restrict__ l_part)
{
    __shared__ alignas(16) u16 Plds[64 * LDP];              // 9216 B
    __shared__ alignas(16) u16 Blds[64 * LDP];              // 9216 B
    __shared__ alignas(16) unsigned char Mlds[64 * MROW];   // 8704 B

    const int tid = threadIdx.x, wave = tid >> 6, lane = tid & 63;
    const int r = tid >> 2, cq = tid & 3;     // row/feat, 16-col chunk
    const int i0 = blockIdx.x * 64, c0 = blockIdx.y * COLS_PER;

    // stage mask window: 64 rows x 128 B, 32 B per thread
    {
        const unsigned char* g = (const unsigned char*)mask64
            + (size_t)(i0 + r) * (N_NODES / 8) + (c0 >> 3) + cq * 32;
        *(uint4*)&Mlds[r * MROW + cq * 32]      = *(const uint4*)g;
        *(uint4*)&Mlds[r * MROW + cq * 32 + 16] = *(const uint4*)(g + 16);
    }

    const float srow = src[i0 + r];
    const float m = lrelu(srow + MBIAS);      // upper bound of row max

    const u16*    whtrow = WhT + (size_t)r * N_NODES + c0 + cq * 16; // r = feat for B
    const float4* dstp   = (const float4*)(dst + c0 + cq * 16);

    const int mrow = lane & 15, kq = (lane >> 4) * 8;

    f32x4 acc[4] = {{0,0,0,0},{0,0,0,0},{0,0,0,0},{0,0,0,0}};
    float lacc = 0.f;

    // prologue B prefetch (tile 0)
    uint4 pb0 = *(const uint4*)(whtrow);
    uint4 pb1 = *(const uint4*)(whtrow + 8);

    __syncthreads();                          // mask window ready
    const u16* mrowp = (const u16*)&Mlds[r * MROW];

    for (int t = 0; t < NTILES; ++t) {
        // stage B tile from prefetch regs
        *(uint4*)&Blds[r * LDP + cq * 16]     = pb0;
        *(uint4*)&Blds[r * LDP + cq * 16 + 8] = pb1;

        // stage P tile: 16 cols/thread; mask bits from LDS, dst from L1
        u32 msk = mrowp[t * 4 + cq];
        float4 d0 = dstp[t * 16],     d1 = dstp[t * 16 + 1];
        float4 d2 = dstp[t * 16 + 2], d3 = dstp[t * 16 + 3];
        float dv[16] = {d0.x,d0.y,d0.z,d0.w, d1.x,d1.y,d1.z,d1.w,
                        d2.x,d2.y,d2.z,d2.w, d3.x,d3.y,d3.z,d3.w};
        u32 po[8];
#pragma unroll
        for (int e = 0; e < 8; ++e) {
            float s0 = lrelu(srow + dv[2 * e]);
            float s1 = lrelu(srow + dv[2 * e + 1]);
            float p0 = (msk & (1u << (2 * e)))     ? __expf(s0 - m) : 0.f;
            float p1 = (msk & (1u << (2 * e + 1))) ? __expf(s1 - m) : 0.f;
            u32 q0 = f2bfbits(p0), q1 = f2bfbits(p1);
            lacc += bf2f(q0) + bf2f(q1);      // l from ROUNDED P
            po[e] = q0 | (q1 << 16);
        }
        *(uint4*)&Plds[r * LDP + cq * 16]     = *(uint4*)&po[0];
        *(uint4*)&Plds[r * LDP + cq * 16 + 8] = *(uint4*)&po[4];

        __syncthreads();

        // prefetch next B tile; stays in flight across the MFMA section
        if (t + 1 < NTILES) {
            pb0 = *(const uint4*)(whtrow + (t + 1) * 64);
            pb1 = *(const uint4*)(whtrow + (t + 1) * 64 + 8);
        }

#pragma unroll
        for (int ks = 0; ks < 2; ++ks) {
            bf16x8 avf = *(bf16x8*)&Plds[(16 * wave + mrow) * LDP + ks * 32 + kq];
#pragma unroll
            for (int nt = 0; nt < 4; ++nt) {
                bf16x8 bvf = *(bf16x8*)&Blds[(16 * nt + mrow) * LDP + ks * 32 + kq];
                acc[nt] = __builtin_amdgcn_mfma_f32_16x16x32_bf16(avf, bvf, acc[nt], 0, 0, 0);
            }
        }
        __syncthreads();
    }

    // partial l: sum over the 4 col-chunk threads of each row
    lacc += __shfl_xor(lacc, 1, 64);
    lacc += __shfl_xor(lacc, 2, 64);
    if (cq == 0) l_part[blockIdx.y * N_NODES + i0 + r] = lacc;

    // C/D layout: col = lane&15, row = (lane>>4)*4 + reg   [m89/m91 verified]
    float* Ob = O_part + (size_t)blockIdx.y * N_NODES * OUT_F;
#pragma unroll
    for (int nt = 0; nt < 4; ++nt)
#pragma unroll
        for (int reg = 0; reg < 4; ++reg) {
            int row = i0 + 16 * wave + (lane >> 4) * 4 + reg;
            int col = 16 * nt + (lane & 15);
            Ob[(size_t)row * OUT_F + col] = acc[nt][reg];
        }
}

// ---------------------------------------------------------------------------
// Kernel 3: out = elu( (sum_c O_c) / (sum_c l_c) ), store per dtype.
// ---------------------------------------------------------------------------
__global__ __launch_bounds__(256) void gat_reduce_kernel(
    const float* __restrict__ O_part, const float* __restrict__ l_part,
    const void* __restrict__ adj, void* __restrict__ out)
{
    int gid = blockIdx.x * 256 + threadIdx.x;
    int i = gid >> 6;
    float O = 0.f, L = 0.f;
#pragma unroll
    for (int c = 0; c < CSPL; ++c) {
        O += O_part[(size_t)c * N_NODES * OUT_F + gid];
        L += l_part[c * N_NODES + i];
    }
    float hp = O / L;
    float o = hp > 0.f ? hp : expm1f(hp);     // elu alpha=1
    if (detect_bf16(adj)) ((u16*)out)[gid] = (u16)f2bfbits(o);
    else                  ((float*)out)[gid] = o;
}

// ---------------------------------------------------------------------------
extern "C" void kernel_launch(void* const* d_in, const int* in_sizes, int n_in,
                              void* d_out, int out_size, void* d_ws, size_t ws_size,
                              hipStream_t stream)
{
    const void* h   = d_in[0];
    const void* adj = d_in[1];
    const void* W   = d_in[2];
    const void* a   = d_in[3];

    char* ws = (char*)d_ws;
    u16*   WhT    = (u16*)ws;                                   // 1 MB
    float* src    = (float*)(ws + (1u << 20));                  // 32 KB
    float* dst    = (float*)(ws + (1u << 20) + 32768);          // 32 KB
    u64*   mask64 = (u64*)  (ws + (2u << 20));                  // 8 MB
    float* O_part = (float*)(ws + (16u << 20));                 // 16 MB (8 splits)
    float* l_part = (float*)(ws + (32u << 20));                 // 256 KB

    gat_prep_kernel<<<WH_BLOCKS + 2048, 256, 0, stream>>>(h, W, a, adj, WhT, src, dst, mask64);
    dim3 grid(N_NODES / 64, CSPL);
    gat_attn_kernel<<<grid, 256, 0, stream>>>(mask64, WhT, src, dst, O_part, l_part);
    gat_reduce_kernel<<<N_NODES * OUT_F / 256, 256, 0, stream>>>(O_part, l_part, adj, d_out);
}